// Round 5
// baseline (2562.681 us; speedup 1.0000x reference)
//
#include <hip/hip_runtime.h>
#include <math.h>

// B=512, T=256, D=81, H=128
#define BB 512
#define TT 256
#define DD 81
#define HH 128

typedef _Float16 half8 __attribute__((ext_vector_type(8)));
typedef float    f32x4 __attribute__((ext_vector_type(4)));

// ---- d_ws blob geometry (float4 units) ----
// [0, 4096): W1 frag chunks (64 chunks x 64 f4)  -> loaded to per-wave registers
// [4096, 5632): W2 frag chunks (24 chunks x 64 f4) -> staged to LDS
// [5632, 5632+14336): W4 register fragments (28 frags x 512 threads), gate-major
#define BLOB_LDS_ELEMS 5632
#define BLOB_W4_ELEMS  14336
#define BLOB_W4_OFF    BLOB_LDS_ELEMS
#define WS_ELEMS       (BLOB_LDS_ELEMS + BLOB_W4_ELEMS)

// ---- LDS layout (bytes) ---- (single batch row per block; 2 blocks/CU target)
#define W2_OFF   0        // 24 KB: 24 chunks (ntile 0..5 x ktile 0..3) x 1 KB
#define HS_OFF   24576    // [256] fp16  [h(128); c(128)]
#define A1_OFF   25088    // [128] fp16
#define E_OFF    25344    // [96] f32
#define ACT_OFF  25728    // [224] fp16: xw(81); h(128); 1; pad
#define LDS_BYTES 26176

__device__ __forceinline__ float wave_sum(float v) {
#pragma unroll
    for (int off = 32; off > 0; off >>= 1) v += __shfl_xor(v, off, 64);
    return v;
}
__device__ __forceinline__ float wave_max(float v) {
#pragma unroll
    for (int off = 32; off > 0; off >>= 1) v = fmaxf(v, __shfl_xor(v, off, 64));
    return v;
}
__device__ __forceinline__ float fast_sig(float x)  { return 1.f / (1.f + __expf(-x)); }
__device__ __forceinline__ float fast_tanh(float x) { return 1.f - 2.f / (__expf(2.f * x) + 1.f); }

__device__ __forceinline__ float4 pack8h(const float* v) {
    union { float4 f4; _Float16 h[8]; } u;
#pragma unroll
    for (int c = 0; c < 8; ++c) u.h[c] = (_Float16)v[c];
    return u.f4;
}

// ---------------- repack kernels ----------------
// B-fragment chunks, 1 KB each, lane l's 16 B at chunk + l*16.
// chunk(nt,kt), lane l: W[n][kb..kb+7] fp16, n = 16*nt + (l&15), kb = 32*kt + (l>>4)*8
__global__ void repack_lds_blob(const float* __restrict__ W1, const float* __restrict__ W2,
                                float4* __restrict__ dst) {
    int tid = blockIdx.x * blockDim.x + threadIdx.x;
    if (tid >= BLOB_LDS_ELEMS) return;
    float v[8];
    if (tid < 4096) {                      // W1 [128][256]
        int c = tid >> 6, l = tid & 63;
        int nt = c >> 3, kt = c & 7;
        int n = 16 * nt + (l & 15);
        int kb = 32 * kt + ((l >> 4) << 3);
#pragma unroll
        for (int c2 = 0; c2 < 8; ++c2) v[c2] = W1[(size_t)n * 256 + kb + c2];
    } else {                               // W2 [81][128], pad n>=81 with 0
        int idx = tid - 4096;
        int c = idx >> 6, l = idx & 63;
        int nt = c >> 2, kt = c & 3;
        int n = 16 * nt + (l & 15);
        int kb = 32 * kt + ((l >> 4) << 3);
#pragma unroll
        for (int c2 = 0; c2 < 8; ++c2)
            v[c2] = (n < 81) ? W2[(size_t)n * 128 + kb + c2] : 0.f;
    }
    dst[tid] = pack8h(v);
}

// W4 register fragments: frag f = j*7+kt (j = GATE index 0..3, kt=0..6), thread r=w*64+l.
// Gate-major remap: n = 128*j + 16*w + (l&15)  -> wave w owns hidden units u=16w..16w+15
// for ALL four gates (reg-direct LSTM pointwise, no gates LDS round-trip).
// k = 32*kt + (l>>4)*8 + c over fused K:
//   k<81: Wih[n][k]; k<209: Whh[n][k-81]; k==209: bih[n]+bhh[n]; else 0.
__global__ void repack_w4(const float* __restrict__ Wih, const float* __restrict__ Whh,
                          const float* __restrict__ bih, const float* __restrict__ bhh,
                          float4* __restrict__ dst) {
    int tid = blockIdx.x * blockDim.x + threadIdx.x;
    if (tid >= BLOB_W4_ELEMS) return;
    int f = tid >> 9, r = tid & 511;
    int w = r >> 6, l = r & 63;
    int j = f / 7, kt = f - 7 * j;
    int n = 128 * j + 16 * w + (l & 15);
    int kb = 32 * kt + ((l >> 4) << 3);
    float v[8];
#pragma unroll
    for (int c = 0; c < 8; ++c) {
        int k = kb + c;
        float x;
        if (k < 81)        x = Wih[(size_t)n * 81 + k];
        else if (k < 209)  x = Whh[(size_t)n * 128 + (k - 81)];
        else if (k == 209) x = bih[n] + bhh[n];
        else               x = 0.f;
        v[c] = x;
    }
    dst[tid] = pack8h(v);
}

// ---------------- main kernel: 512 blocks x 512 threads, 1 row/block ----------------
// 2 blocks co-resident per CU (LDS ~26 KB, VGPR <= 128) -> inter-block latency hiding.
__global__ __launch_bounds__(512, 4)
void encoder_kernel(const float* __restrict__ X,
                    const float* __restrict__ b1, const float* __restrict__ b2,
                    const float4* __restrict__ wlds, const float4* __restrict__ w4q,
                    float* __restrict__ out_h, float* __restrict__ out_alpha) {
    const int tid = threadIdx.x;
    const int w   = tid >> 6;
    const int l   = tid & 63;
    const int b   = blockIdx.x;           // one batch row per block

    __shared__ __align__(16) unsigned char lds[LDS_BYTES];

    // stage W2 fragment chunks into LDS (24 KB = 3 x 512 float4)
#pragma unroll
    for (int i = 0; i < 3; ++i)
        ((float4*)lds)[i * 512 + tid] = wlds[4096 + i * 512 + tid];

    // resident W1 B-fragments for this wave's n-tile (8 x half8; R3-validated path)
    half8 wb1[8];
#pragma unroll
    for (int kt = 0; kt < 8; ++kt) {
        float4 tt = wlds[(w * 8 + kt) * 64 + l];
        wb1[kt] = *(half8*)&tt;
    }

    // resident W4 B-fragments (gate-major mapping)
    half8 wf[4][7];
#pragma unroll
    for (int j = 0; j < 4; ++j)
#pragma unroll
        for (int kt = 0; kt < 7; ++kt) {
            float4 tt = w4q[(j * 7 + kt) * 512 + tid];
            wf[j][kt] = *(half8*)&tt;
        }

    // per-thread biases
    const float breg1 = b1[16 * w + (l & 15)];
    const int   n2    = 16 * w + (l & 15);
    const float breg2 = (n2 < 81) ? b2[n2] : 0.f;

    // init state (single row)
    if (tid < 256) ((unsigned short*)(lds + HS_OFF))[tid] = 0;        // h,c fp16 = 0
    if (tid < 224) {
        ((_Float16*)(lds + ACT_OFF))[tid] = (tid == 209) ? (_Float16)1.0f : (_Float16)0.0f;
    }
    float creg = 0.f;   // persistent cell state, lanes l<16: unit u = 16w+l
    __syncthreads();

#pragma unroll 1
    for (int t = 0; t < TT; ++t) {
        // prefetch x_t (wave 0; consumed in phase 3 after 2 barriers)
        float xv0 = 0.f, xv1 = 0.f;
        if (w == 0) {
            const float* xp = X + ((size_t)b * TT + t) * DD;
            xv0 = xp[l];
            if (l < DD - 64) xv1 = xp[l + 64];
        }

        // ---- phase 1: a1 = tanh(W1 @ [h;c] + b1); wave w owns n-tile w (16 outputs)
        {
            const unsigned offA = HS_OFF + (l >> 4) * 16;   // single row, all A-rows dup
            f32x4 ae = {0.f, 0.f, 0.f, 0.f}, ao = {0.f, 0.f, 0.f, 0.f};
#pragma unroll
            for (int kt = 0; kt < 8; ++kt) {
                half8 a = *(const half8*)(lds + offA + kt * 64);
                if (kt & 1) ao = __builtin_amdgcn_mfma_f32_16x16x32_f16(a, wb1[kt], ao, 0, 0, 0);
                else        ae = __builtin_amdgcn_mfma_f32_16x16x32_f16(a, wb1[kt], ae, 0, 0, 0);
            }
            if (l < 16) {
                _Float16* a1f = (_Float16*)(lds + A1_OFF);
                a1f[16 * w + l] = (_Float16)fast_tanh(ae[0] + ao[0] + breg1);
            }
        }
        __syncthreads();

        // ---- phase 2: e = W2 @ a1 + b2; waves 0..5, nt = w
        if (w < 6) {
            const unsigned offA = (l >> 4) * 16;
            f32x4 ae = {0.f, 0.f, 0.f, 0.f}, ao = {0.f, 0.f, 0.f, 0.f};
#pragma unroll
            for (int kt = 0; kt < 4; ++kt) {
                half8 a = *(const half8*)(lds + A1_OFF + offA + kt * 64);
                half8 bf = *(const half8*)(lds + W2_OFF + (w * 4 + kt) * 1024 + l * 16);
                if (kt & 1) ao = __builtin_amdgcn_mfma_f32_16x16x32_f16(a, bf, ao, 0, 0, 0);
                else        ae = __builtin_amdgcn_mfma_f32_16x16x32_f16(a, bf, ae, 0, 0, 0);
            }
            if (l < 16)
                ((float*)(lds + E_OFF))[16 * w + l] = ae[0] + ao[0] + breg2;
        }
        __syncthreads();

        // ---- phase 3: softmax + xw; wave 0
        if (w == 0) {
            const float* er = (const float*)(lds + E_OFF);
            float ev0 = er[l];
            float ev1 = (l < DD - 64) ? er[l + 64] : -INFINITY;
            float m  = wave_max(fmaxf(ev0, ev1));
            float p0 = __expf(ev0 - m);
            float p1 = (l < DD - 64) ? __expf(ev1 - m) : 0.f;
            float inv = 1.f / wave_sum(p0 + p1);
            _Float16* act = (_Float16*)(lds + ACT_OFF);
            float* oa = out_alpha + ((size_t)b * TT + t) * DD;
            float al0 = p0 * inv;
            act[l] = (_Float16)(al0 * xv0);
            oa[l] = al0;
            if (l < DD - 64) {
                float al1 = p1 * inv;
                act[l + 64] = (_Float16)(al1 * xv1);
                oa[l + 64] = al1;
            }
        }
        __syncthreads();

        // ---- phase 4: gates = [xw;h;1] @ W4^T (gate-major); results stay in regs
        f32x4 g0 = {0.f,0.f,0.f,0.f}, g1 = g0, g2 = g0, g3 = g0;
        {
            const unsigned offA = ACT_OFF + (l >> 4) * 16;
            half8 a4[7];
#pragma unroll
            for (int kt = 0; kt < 7; ++kt)
                a4[kt] = *(const half8*)(lds + offA + kt * 64);
#pragma unroll
            for (int kt = 0; kt < 7; ++kt) {
                g0 = __builtin_amdgcn_mfma_f32_16x16x32_f16(a4[kt], wf[0][kt], g0, 0, 0, 0);
                g1 = __builtin_amdgcn_mfma_f32_16x16x32_f16(a4[kt], wf[1][kt], g1, 0, 0, 0);
                g2 = __builtin_amdgcn_mfma_f32_16x16x32_f16(a4[kt], wf[2][kt], g2, 0, 0, 0);
                g3 = __builtin_amdgcn_mfma_f32_16x16x32_f16(a4[kt], wf[3][kt], g3, 0, 0, 0);
            }
        }
        __syncthreads();   // all ACT reads complete before h-writes below (proven skeleton)

        // ---- phase 5: LSTM pointwise; lanes l<16 of each wave, unit u = 16w+l
        if (l < 16) {
            const int u = 16 * w + l;
            float cn = fast_sig(g1[0]) * creg + fast_sig(g0[0]) * fast_tanh(g2[0]);
            float hn = fast_sig(g3[0]) * fast_tanh(cn);
            creg = cn;
            _Float16* hsp = (_Float16*)(lds + HS_OFF);
            hsp[u]       = (_Float16)hn;
            hsp[128 + u] = (_Float16)cn;
            ((_Float16*)(lds + ACT_OFF))[81 + u] = (_Float16)hn;
            out_h[((size_t)b * TT + t) * HH + u] = hn;
        }
        __syncthreads();
    }
}

extern "C" void kernel_launch(void* const* d_in, const int* in_sizes, int n_in,
                              void* d_out, int out_size, void* d_ws, size_t ws_size,
                              hipStream_t stream) {
    const float* X   = (const float*)d_in[0];
    const float* W1  = (const float*)d_in[1];
    const float* b1  = (const float*)d_in[2];
    const float* W2  = (const float*)d_in[3];
    const float* b2  = (const float*)d_in[4];
    const float* Wih = (const float*)d_in[5];
    const float* Whh = (const float*)d_in[6];
    const float* bih = (const float*)d_in[7];
    const float* bhh = (const float*)d_in[8];

    if (ws_size < (size_t)WS_ELEMS * sizeof(float4)) return;  // ~320 KB scratch

    float4* blob = (float4*)d_ws;
    float4* wlds = blob;
    float4* w4q  = blob + BLOB_W4_OFF;

    repack_lds_blob<<<(BLOB_LDS_ELEMS + 255) / 256, 256, 0, stream>>>(W1, W2, wlds);
    repack_w4<<<(BLOB_W4_ELEMS + 255) / 256, 256, 0, stream>>>(Wih, Whh, bih, bhh, w4q);

    float* out_h     = (float*)d_out;                        // [512,256,128]
    float* out_alpha = (float*)d_out + (size_t)BB * TT * HH; // [512,256,81]

    encoder_kernel<<<BB, 512, 0, stream>>>(X, b1, b2, wlds, w4q, out_h, out_alpha);
}

// Round 6
// 646.119 us; speedup vs baseline: 3.9663x; 3.9663x over previous
//
#include <hip/hip_runtime.h>
#include <math.h>

// B=512, T=256, D=81, H=128
#define BB 512
#define TT 256
#define DD 81
#define HH 128

typedef _Float16 half8 __attribute__((ext_vector_type(8)));
typedef float    f32x4 __attribute__((ext_vector_type(4)));

// ---- d_ws blob geometry (float4 units) ----
// [0, 5632): LDS image = W1 frag chunks (4096) + W2 frag chunks (1536)
// [5632, 5632+14336): W4 register fragments (28 frags x 512 threads)
#define BLOB_LDS_ELEMS 5632
#define BLOB_W4_ELEMS  14336
#define BLOB_W4_OFF    BLOB_LDS_ELEMS
#define WS_ELEMS       (BLOB_LDS_ELEMS + BLOB_W4_ELEMS)

// ---- LDS layout (bytes) ----
#define W1_OFF   0        // 64 KB: 64 chunks (ntile 0..7 x ktile 0..7) x 1 KB
#define W2_OFF   65536    // 24 KB: 24 chunks (ntile 0..5 x ktile 0..3) x 1 KB
#define HS_OFF   90112    // [2][256] fp16  [h;c], row stride 512 B
#define ACT_OFF  91136    // [2][224] fp16  [xw(81); h(128); 1; 0-pad], stride 448 B
#define A1_OFF   92032    // [2][128] fp16, row stride 256 B
#define E_OFF    92544    // [2][96] f32  (holds exp(e))
#define GATE_OFF 93312    // [2][512] f32
#define C_OFF    97408    // [2][128] f32
#define LDS_BYTES 98432

__device__ __forceinline__ float wave_sum(float v) {
#pragma unroll
    for (int off = 32; off > 0; off >>= 1) v += __shfl_xor(v, off, 64);
    return v;
}
__device__ __forceinline__ float fast_sig(float x)  { return 1.f / (1.f + __expf(-x)); }
__device__ __forceinline__ float fast_tanh(float x) { return 1.f - 2.f / (__expf(2.f * x) + 1.f); }

__device__ __forceinline__ float4 pack8h(const float* v) {
    union { float4 f4; _Float16 h[8]; } u;
#pragma unroll
    for (int c = 0; c < 8; ++c) u.h[c] = (_Float16)v[c];
    return u.f4;
}

// ---------------- repack kernels (round-0 verbatim) ----------------
// LDS image: B-fragment chunks, 1 KB each, lane l's 16 B at chunk + l*16.
// Fragment content for chunk(nt,kt), lane l: W[n][kb..kb+7] fp16,
//   n = 16*nt + (l&15), kb = 32*kt + (l>>4)*8
__global__ void repack_lds_blob(const float* __restrict__ W1, const float* __restrict__ W2,
                                float4* __restrict__ dst) {
    int tid = blockIdx.x * blockDim.x + threadIdx.x;
    if (tid >= BLOB_LDS_ELEMS) return;
    float v[8];
    if (tid < 4096) {                      // W1 [128][256]
        int c = tid >> 6, l = tid & 63;
        int nt = c >> 3, kt = c & 7;
        int n = 16 * nt + (l & 15);
        int kb = 32 * kt + ((l >> 4) << 3);
#pragma unroll
        for (int c2 = 0; c2 < 8; ++c2) v[c2] = W1[(size_t)n * 256 + kb + c2];
    } else {                               // W2 [81][128], pad n>=81 with 0
        int idx = tid - 4096;
        int c = idx >> 6, l = idx & 63;
        int nt = c >> 2, kt = c & 3;
        int n = 16 * nt + (l & 15);
        int kb = 32 * kt + ((l >> 4) << 3);
#pragma unroll
        for (int c2 = 0; c2 < 8; ++c2)
            v[c2] = (n < 81) ? W2[(size_t)n * 128 + kb + c2] : 0.f;
    }
    dst[tid] = pack8h(v);
}

// W4 register fragments: frag f = j*7+kt (j=n-subtile 0..3, kt=0..6), thread r=w*64+l.
// n = 64*w + 16*j + (l&15); k = 32*kt + (l>>4)*8 + c over fused K:
//   k<81: Wih[n][k]; k<209: Whh[n][k-81]; k==209: bih[n]+bhh[n]; else 0.
__global__ void repack_w4(const float* __restrict__ Wih, const float* __restrict__ Whh,
                          const float* __restrict__ bih, const float* __restrict__ bhh,
                          float4* __restrict__ dst) {
    int tid = blockIdx.x * blockDim.x + threadIdx.x;
    if (tid >= BLOB_W4_ELEMS) return;
    int f = tid >> 9, r = tid & 511;
    int w = r >> 6, l = r & 63;
    int j = f / 7, kt = f - 7 * j;
    int n = 64 * w + 16 * j + (l & 15);
    int kb = 32 * kt + ((l >> 4) << 3);
    float v[8];
#pragma unroll
    for (int c = 0; c < 8; ++c) {
        int k = kb + c;
        float x;
        if (k < 81)        x = Wih[(size_t)n * 81 + k];
        else if (k < 209)  x = Whh[(size_t)n * 128 + (k - 81)];
        else if (k == 209) x = bih[n] + bhh[n];
        else               x = 0.f;
        v[c] = x;
    }
    dst[tid] = pack8h(v);
}

// ---------------- main kernel: 256 blocks x 512 threads, 2 rows/block ----------------
__global__ __launch_bounds__(512, 2)
void encoder_kernel(const float* __restrict__ X,
                    const float* __restrict__ b1, const float* __restrict__ b2,
                    const float4* __restrict__ wlds, const float4* __restrict__ w4q,
                    float* __restrict__ out_h, float* __restrict__ out_alpha) {
    const int tid = threadIdx.x;
    const int w   = tid >> 6;
    const int l   = tid & 63;
    const int b0  = blockIdx.x * 2;

    __shared__ __align__(16) unsigned char lds[LDS_BYTES];

    // stage W1/W2 fragment chunks into LDS (90112 B = 11 x 512 float4)
#pragma unroll
    for (int i = 0; i < 11; ++i)
        ((float4*)lds)[i * 512 + tid] = wlds[i * 512 + tid];

    // load resident W4 B-fragments (112 VGPRs)
    half8 wf[4][7];
#pragma unroll
    for (int j = 0; j < 4; ++j)
#pragma unroll
        for (int kt = 0; kt < 7; ++kt) {
            float4 t = w4q[(j * 7 + kt) * 512 + tid];
            wf[j][kt] = *(half8*)&t;
        }

    // per-thread biases (used by lanes l<16 only)
    const float breg1 = b1[16 * w + (l & 15)];
    const int   n2    = 16 * w + (l & 15);
    const float breg2 = (n2 < 81) ? b2[n2] : 0.f;

    // init state
    if (tid < 512) ((unsigned short*)(lds + HS_OFF))[tid] = 0;   // h,c fp16 = 0
    if (tid < 448) {                                             // act: zeros, [209]=1
        int r = tid / 224, i = tid - r * 224;
        ((_Float16*)(lds + ACT_OFF))[r * 224 + i] = (i == 209) ? (_Float16)1.0f : (_Float16)0.0f;
    }
    if (tid < 256) ((float*)(lds + C_OFF))[tid] = 0.f;           // c fp32 = 0

    // prefetch x for t=0 (waves 0,1 = rows 0,1); refreshed in phase 3 each step
    float xv0 = 0.f, xv1 = 0.f;
    if (w < 2) {
        const float* xr = X + ((size_t)(b0 + w) * TT + 0) * DD;
        xv0 = xr[l];
        if (l < DD - 64) xv1 = xr[l + 64];
    }
    __syncthreads();

#pragma unroll 1
    for (int t = 0; t < TT; ++t) {
        // ---- phase 1: a1 = tanh(W1 @ [h;c] + b1); wave w owns n-tile w
        {
            const unsigned offA = (l & 1) * 512 + (l >> 4) * 16;
            f32x4 ae = {0.f, 0.f, 0.f, 0.f}, ao = {0.f, 0.f, 0.f, 0.f};
#pragma unroll
            for (int kt = 0; kt < 8; ++kt) {
                half8 a = *(const half8*)(lds + HS_OFF + offA + kt * 64);
                half8 b = *(const half8*)(lds + W1_OFF + (w * 8 + kt) * 1024 + l * 16);
                if (kt & 1) ao = __builtin_amdgcn_mfma_f32_16x16x32_f16(a, b, ao, 0, 0, 0);
                else        ae = __builtin_amdgcn_mfma_f32_16x16x32_f16(a, b, ae, 0, 0, 0);
            }
            if (l < 16) {
                _Float16* a1f = (_Float16*)(lds + A1_OFF);
                float v0 = fast_tanh(ae[0] + ao[0] + breg1);
                float v1 = fast_tanh(ae[1] + ao[1] + breg1);
                a1f[16 * w + l]       = (_Float16)v0;
                a1f[128 + 16 * w + l] = (_Float16)v1;
            }
        }
        __syncthreads();

        // ---- phase 2: es = exp(W2 @ a1 + b2); waves 0..5
        //      (|e| <= ||W2 row||_1 + |b2| < 12, so exp is fp32-safe without max-sub;
        //       exp runs here on 6 parallel waves, off the phase-3 critical chain)
        if (w < 6) {
            const unsigned offA = (l & 1) * 256 + (l >> 4) * 16;
            f32x4 ae = {0.f, 0.f, 0.f, 0.f}, ao = {0.f, 0.f, 0.f, 0.f};
#pragma unroll
            for (int kt = 0; kt < 4; ++kt) {
                half8 a = *(const half8*)(lds + A1_OFF + offA + kt * 64);
                half8 b = *(const half8*)(lds + W2_OFF + (w * 4 + kt) * 1024 + l * 16);
                if (kt & 1) ao = __builtin_amdgcn_mfma_f32_16x16x32_f16(a, b, ao, 0, 0, 0);
                else        ae = __builtin_amdgcn_mfma_f32_16x16x32_f16(a, b, ae, 0, 0, 0);
            }
            if (l < 16) {
                float* es = (float*)(lds + E_OFF);
                es[16 * w + l]      = __expf(ae[0] + ao[0] + breg2);
                es[96 + 16 * w + l] = __expf(ae[1] + ao[1] + breg2);
            }
        }

        // ---- early A-fragment reads for phase 4, kt=3..6 (k=96..223: pure h(t-1)/bias,
        //      stable since the loop-end barrier; hides their LDS latency under p2/p3)
        half8 a4h[4];
        {
            const unsigned offA = ACT_OFF + (l & 1) * 448 + (l >> 4) * 16;
#pragma unroll
            for (int kt = 0; kt < 4; ++kt)
                a4h[kt] = *(const half8*)(lds + offA + (kt + 3) * 64);
        }
        __syncthreads();

        // ---- phase 3: sum + alpha + xw; wave r handles row r (max-free softmax)
        if (w < 2) {
            const float* er = (const float*)(lds + E_OFF) + w * 96;
            float p0 = er[l];                                  // exp(e[l])
            float p1 = (l < DD - 64) ? er[l + 64] : 0.f;
            float inv = 1.f / wave_sum(p0 + p1);
            _Float16* act = (_Float16*)(lds + ACT_OFF) + w * 224;
            float* oa = out_alpha + ((size_t)(b0 + w) * TT + t) * DD;
            float al0 = p0 * inv;
            act[l] = (_Float16)(al0 * xv0);
            oa[l] = al0;
            if (l < DD - 64) {
                float al1 = p1 * inv;
                act[l + 64] = (_Float16)(al1 * xv1);
                oa[l + 64] = al1;
            }
            // prefetch x for t+1 (full step of latency cover)
            int tn = (t + 1 < TT) ? t + 1 : t;
            const float* xr = X + ((size_t)(b0 + w) * TT + tn) * DD;
            xv0 = xr[l];
            if (l < DD - 64) xv1 = xr[l + 64];
        }
        __syncthreads();

        // ---- phase 4: gates = [xw;h;1] @ W4^T (bias folded); wave w owns gates [64w,64w+64)
        {
            const unsigned offA = (l & 1) * 448 + (l >> 4) * 16;
            half8 a4[3];
#pragma unroll
            for (int kt = 0; kt < 3; ++kt)
                a4[kt] = *(const half8*)(lds + ACT_OFF + offA + kt * 64);
            f32x4 g0 = {0.f,0.f,0.f,0.f}, g1 = g0, g2 = g0, g3 = g0;
#pragma unroll
            for (int kt = 0; kt < 7; ++kt) {
                half8 a = (kt < 3) ? a4[kt] : a4h[kt - 3];
                g0 = __builtin_amdgcn_mfma_f32_16x16x32_f16(a, wf[0][kt], g0, 0, 0, 0);
                g1 = __builtin_amdgcn_mfma_f32_16x16x32_f16(a, wf[1][kt], g1, 0, 0, 0);
                g2 = __builtin_amdgcn_mfma_f32_16x16x32_f16(a, wf[2][kt], g2, 0, 0, 0);
                g3 = __builtin_amdgcn_mfma_f32_16x16x32_f16(a, wf[3][kt], g3, 0, 0, 0);
            }
            if (l < 16) {
                float* gs = (float*)(lds + GATE_OFF);
                gs[       64 * w      + l] = g0[0]; gs[512 + 64 * w      + l] = g0[1];
                gs[       64 * w + 16 + l] = g1[0]; gs[512 + 64 * w + 16 + l] = g1[1];
                gs[       64 * w + 32 + l] = g2[0]; gs[512 + 64 * w + 32 + l] = g2[1];
                gs[       64 * w + 48 + l] = g3[0]; gs[512 + 64 * w + 48 + l] = g3[1];
            }
        }
        __syncthreads();

        // ---- phase 5: LSTM pointwise; update h,c
        if (tid < 256) {
            int r = tid >> 7, u = tid & 127;
            const float* gs = (const float*)(lds + GATE_OFF) + r * 512;
            float gi = gs[u], gf = gs[u + 128], gg = gs[u + 256], go = gs[u + 384];
            float* cs = (float*)(lds + C_OFF) + r * 128;
            float cn = fast_sig(gf) * cs[u] + fast_sig(gi) * fast_tanh(gg);
            float hn = fast_sig(go) * fast_tanh(cn);
            cs[u] = cn;
            _Float16 hh = (_Float16)hn, ch = (_Float16)cn;
            _Float16* hsr = (_Float16*)(lds + HS_OFF) + r * 256;
            hsr[u] = hh; hsr[128 + u] = ch;
            ((_Float16*)(lds + ACT_OFF))[r * 224 + 81 + u] = hh;
            out_h[((size_t)(b0 + r) * TT + t) * HH + u] = hn;
        }
        __syncthreads();
    }
}

extern "C" void kernel_launch(void* const* d_in, const int* in_sizes, int n_in,
                              void* d_out, int out_size, void* d_ws, size_t ws_size,
                              hipStream_t stream) {
    const float* X   = (const float*)d_in[0];
    const float* W1  = (const float*)d_in[1];
    const float* b1  = (const float*)d_in[2];
    const float* W2  = (const float*)d_in[3];
    const float* b2  = (const float*)d_in[4];
    const float* Wih = (const float*)d_in[5];
    const float* Whh = (const float*)d_in[6];
    const float* bih = (const float*)d_in[7];
    const float* bhh = (const float*)d_in[8];

    if (ws_size < (size_t)WS_ELEMS * sizeof(float4)) return;  // ~320 KB scratch

    float4* blob = (float4*)d_ws;
    float4* wlds = blob;
    float4* w4q  = blob + BLOB_W4_OFF;

    repack_lds_blob<<<(BLOB_LDS_ELEMS + 255) / 256, 256, 0, stream>>>(W1, W2, wlds);
    repack_w4<<<(BLOB_W4_ELEMS + 255) / 256, 256, 0, stream>>>(Wih, Whh, bih, bhh, w4q);

    float* out_h     = (float*)d_out;                        // [512,256,128]
    float* out_alpha = (float*)d_out + (size_t)BB * TT * HH; // [512,256,81]

    encoder_kernel<<<BB / 2, 512, 0, stream>>>(X, b1, b2, wlds, w4q, out_h, out_alpha);
}